// Round 1
// baseline (695.583 us; speedup 1.0000x reference)
//
#include <hip/hip_runtime.h>

#define EN   500000
#define DN   128          // node feature dim == edge feature dim
#define DIN  384          // 2*DN + DE
#define HID  64
#define NTILES 31250      // EN / 16 (exact)

typedef __attribute__((ext_vector_type(8))) short bf16x8;
typedef __attribute__((ext_vector_type(4))) float f32x4;

__device__ __forceinline__ short f2bf(float f) {
    union { float f; unsigned u; } v; v.f = f;
    return (short)((v.u + 0x7FFFu + ((v.u >> 16) & 1u)) >> 16);  // RNE
}

// Transpose + bf16-convert weights into workspace:
// W1 [384,64] f32 -> W1T [64][384] bf16 ; W2 [64,128] f32 -> W2T [128][64] bf16
__global__ void prep_weights(const float* __restrict__ W1, const float* __restrict__ W2,
                             short* __restrict__ W1T, short* __restrict__ W2T) {
    int i = blockIdx.x * 256 + threadIdx.x;
    if (i < DIN * HID) {
        int k = i / HID, n = i % HID;          // W1[k][n]
        W1T[n * DIN + k] = f2bf(W1[i]);
    }
    if (i < HID * DN) {
        int k = i / DN, d = i % DN;            // W2[k][d]
        W2T[d * HID + k] = f2bf(W2[i]);
    }
}

__global__ __launch_bounds__(256, 3)
void edge_update(const float* __restrict__ x, const int* __restrict__ ei,
                 const float* __restrict__ e, const float* __restrict__ b1,
                 const float* __restrict__ b2, const short* __restrict__ W1T,
                 const short* __restrict__ W2T, float* __restrict__ out) {
    // per-wave h re-layout buffer: 16 rows x 72 bf16 (stride-padded)
    __shared__ short hbuf[4][16 * 72];

    const int tid  = threadIdx.x;
    const int wave = tid >> 6;
    const int lane = tid & 63;
    const int m    = lane & 15;      // A-row / B-col within fragment
    const int q    = lane >> 4;      // quad
    const int kq   = q * 8;

    short* hb = &hbuf[wave][0];

    for (int t = 0; t < 2; ++t) {
        const int tile = blockIdx.x * 8 + wave * 2 + t;
        if (tile >= NTILES) continue;
        const int ebase = tile * 16;
        const int edge  = ebase + m;

        const int src = ei[edge];
        const int dst = ei[EN + edge];
        const float* rsrc = x + (size_t)src  * DN;
        const float* rdst = x + (size_t)dst  * DN;
        const float* rede = e + (size_t)edge * DN;

        // ---------------- GEMM1: [16,384] @ [384,64] -> h[16,64] ----------------
        f32x4 acc1[4];
        #pragma unroll
        for (int nt = 0; nt < 4; ++nt) acc1[nt] = (f32x4){0.f, 0.f, 0.f, 0.f};

        #pragma unroll
        for (int reg = 0; reg < 3; ++reg) {
            const float* rp = (reg == 0) ? rsrc : (reg == 1) ? rdst : rede;
            #pragma unroll
            for (int ks = 0; ks < 4; ++ks) {
                const float* ap = rp + ks * 32 + kq;
                f32x4 v0 = *(const f32x4*)ap;
                f32x4 v1 = *(const f32x4*)(ap + 4);
                bf16x8 a;
                a[0] = f2bf(v0[0]); a[1] = f2bf(v0[1]); a[2] = f2bf(v0[2]); a[3] = f2bf(v0[3]);
                a[4] = f2bf(v1[0]); a[5] = f2bf(v1[1]); a[6] = f2bf(v1[2]); a[7] = f2bf(v1[3]);
                const int kglob = (reg * 4 + ks) * 32 + kq;
                #pragma unroll
                for (int nt = 0; nt < 4; ++nt) {
                    bf16x8 b = *(const bf16x8*)(W1T + (m + 16 * nt) * DIN + kglob);
                    acc1[nt] = __builtin_amdgcn_mfma_f32_16x16x32_bf16(a, b, acc1[nt], 0, 0, 0);
                }
            }
        }

        // bias + ReLU, write h to LDS in row-major [row][hid] (C-layout -> A-layout)
        #pragma unroll
        for (int nt = 0; nt < 4; ++nt) {
            const int col = m + 16 * nt;
            const float bv = b1[col];
            #pragma unroll
            for (int r = 0; r < 4; ++r) {
                float h = acc1[nt][r] + bv;
                h = h > 0.f ? h : 0.f;
                hb[(q * 4 + r) * 72 + col] = f2bf(h);
            }
        }

        // ---------------- GEMM2: h[16,64] @ [64,128] -> [16,128] ----------------
        bf16x8 a0 = *(const bf16x8*)(hb + m * 72 + kq);
        bf16x8 a1 = *(const bf16x8*)(hb + m * 72 + 32 + kq);

        f32x4 acc2[8];
        #pragma unroll
        for (int nt = 0; nt < 8; ++nt) acc2[nt] = (f32x4){0.f, 0.f, 0.f, 0.f};

        #pragma unroll
        for (int nt = 0; nt < 8; ++nt) {
            const short* wp = W2T + (m + 16 * nt) * HID + kq;
            bf16x8 b0 = *(const bf16x8*)wp;
            bf16x8 b1v = *(const bf16x8*)(wp + 32);
            acc2[nt] = __builtin_amdgcn_mfma_f32_16x16x32_bf16(a0, b0,  acc2[nt], 0, 0, 0);
            acc2[nt] = __builtin_amdgcn_mfma_f32_16x16x32_bf16(a1, b1v, acc2[nt], 0, 0, 0);
        }

        // ---------------- epilogue: out = e + (h@W2) + b2 ----------------
        #pragma unroll
        for (int nt = 0; nt < 8; ++nt) {
            const int d = m + 16 * nt;
            const float bv = b2[d];
            #pragma unroll
            for (int r = 0; r < 4; ++r) {
                const size_t idx = (size_t)(ebase + q * 4 + r) * DN + d;
                out[idx] = e[idx] + acc2[nt][r] + bv;
            }
        }
    }
}

extern "C" void kernel_launch(void* const* d_in, const int* in_sizes, int n_in,
                              void* d_out, int out_size, void* d_ws, size_t ws_size,
                              hipStream_t stream) {
    const float* x  = (const float*)d_in[0];
    const int*   ei = (const int*)d_in[1];     // edge_index [2, E] int32
    const float* e  = (const float*)d_in[2];
    const float* W1 = (const float*)d_in[3];
    const float* b1 = (const float*)d_in[4];
    const float* W2 = (const float*)d_in[5];
    const float* b2 = (const float*)d_in[6];
    float* out = (float*)d_out;

    short* W1T = (short*)d_ws;                 // 64*384 bf16 = 49152 B
    short* W2T = W1T + HID * DIN;              // 128*64 bf16 = 16384 B

    prep_weights<<<96, 256, 0, stream>>>(W1, W2, W1T, W2T);

    const int nblocks = (NTILES + 7) / 8;      // 8 tiles (128 edges) per block
    edge_update<<<nblocks, 256, 0, stream>>>(x, ei, e, b1, b2, W1T, W2T, out);
}

// Round 2
// 672.530 us; speedup vs baseline: 1.0343x; 1.0343x over previous
//
#include <hip/hip_runtime.h>

#define NN   50000        // nodes
#define EN   500000       // edges
#define DN   128          // node feature dim == edge feature dim
#define DIN  384          // 2*DN + DE
#define HID  64
#define NTILES 31250      // EN / 16 (exact)
#define EST  132          // ebuf row stride in floats (padded: +4 breaks bank aliasing)

typedef __attribute__((ext_vector_type(8))) short bf16x8;
typedef __attribute__((ext_vector_type(4))) float f32x4;

__device__ __forceinline__ short f2bf(float f) {
    union { float f; unsigned u; } v; v.f = f;
    return (short)((v.u + 0x7FFFu + ((v.u >> 16) & 1u)) >> 16);  // RNE
}

// W1 [384,64] f32 -> W1T [64][384] bf16 ; W2 [64,128] f32 -> W2T [128][64] bf16
__global__ void prep_weights(const float* __restrict__ W1, const float* __restrict__ W2,
                             short* __restrict__ W1T, short* __restrict__ W2T) {
    int i = blockIdx.x * 256 + threadIdx.x;
    if (i < DIN * HID) {
        int k = i / HID, n = i % HID;
        W1T[n * DIN + k] = f2bf(W1[i]);
    }
    if (i < HID * DN) {
        int k = i / DN, d = i % DN;
        W2T[d * HID + k] = f2bf(W2[i]);
    }
}

// x [NN,128] f32 -> xb [NN,128] bf16 (halves gather bytes, removes inner-loop converts)
__global__ void prep_x(const float* __restrict__ x, short* __restrict__ xb) {
    int i = blockIdx.x * 256 + threadIdx.x;   // one thread per 8 elements
    if (i >= NN * DN / 8) return;
    const float* p = x + (size_t)i * 8;
    f32x4 v0 = *(const f32x4*)p;
    f32x4 v1 = *(const f32x4*)(p + 4);
    bf16x8 o;
    o[0] = f2bf(v0[0]); o[1] = f2bf(v0[1]); o[2] = f2bf(v0[2]); o[3] = f2bf(v0[3]);
    o[4] = f2bf(v1[0]); o[5] = f2bf(v1[1]); o[6] = f2bf(v1[2]); o[7] = f2bf(v1[3]);
    *(bf16x8*)(xb + (size_t)i * 8) = o;
}

template<bool XB>
__global__ __launch_bounds__(256, 3)
void edge_update(const float* __restrict__ x, const short* __restrict__ xb,
                 const int* __restrict__ ei, const float* __restrict__ e,
                 const float* __restrict__ b1, const float* __restrict__ b2,
                 const short* __restrict__ W1T, const short* __restrict__ W2T,
                 float* __restrict__ out) {
    __shared__ float ebuf[4][16 * EST];   // e-tile stash: epilogue residual from LDS
    __shared__ short hbuf[4][16 * 72];    // h re-layout (C-layout -> A-layout)

    const int tid  = threadIdx.x;
    const int wave = tid >> 6;
    const int lane = tid & 63;
    const int m    = lane & 15;      // A-row / B-col within fragment
    const int q    = lane >> 4;      // quad
    const int kq   = q * 8;

    float* eb = &ebuf[wave][0];
    short* hb = &hbuf[wave][0];

    for (int t = 0; t < 2; ++t) {
        const int tile = blockIdx.x * 8 + wave * 2 + t;
        if (tile >= NTILES) continue;
        const int ebase = tile * 16;
        const int edge  = ebase + m;

        const int src = ei[edge];
        const int dst = ei[EN + edge];

        // ---- issue ALL per-tile input loads up front (16 x 16B in flight) ----
        bf16x8 as[4], ad[4], ae[4];
        if (XB) {
            const short* ps = xb + (size_t)src * DN;
            const short* pd = xb + (size_t)dst * DN;
            #pragma unroll
            for (int ks = 0; ks < 4; ++ks) {
                as[ks] = *(const bf16x8*)(ps + ks * 32 + kq);
                ad[ks] = *(const bf16x8*)(pd + ks * 32 + kq);
            }
        } else {
            const float* rs = x + (size_t)src * DN;
            const float* rd = x + (size_t)dst * DN;
            #pragma unroll
            for (int ks = 0; ks < 4; ++ks) {
                f32x4 s0 = *(const f32x4*)(rs + ks * 32 + kq);
                f32x4 s1 = *(const f32x4*)(rs + ks * 32 + kq + 4);
                f32x4 d0 = *(const f32x4*)(rd + ks * 32 + kq);
                f32x4 d1 = *(const f32x4*)(rd + ks * 32 + kq + 4);
                bf16x8 a, b;
                a[0]=f2bf(s0[0]); a[1]=f2bf(s0[1]); a[2]=f2bf(s0[2]); a[3]=f2bf(s0[3]);
                a[4]=f2bf(s1[0]); a[5]=f2bf(s1[1]); a[6]=f2bf(s1[2]); a[7]=f2bf(s1[3]);
                b[0]=f2bf(d0[0]); b[1]=f2bf(d0[1]); b[2]=f2bf(d0[2]); b[3]=f2bf(d0[3]);
                b[4]=f2bf(d1[0]); b[5]=f2bf(d1[1]); b[6]=f2bf(d1[2]); b[7]=f2bf(d1[3]);
                as[ks] = a; ad[ks] = b;
            }
        }

        const float* re = e + (size_t)edge * DN;
        f32x4 ev[8];
        #pragma unroll
        for (int ks = 0; ks < 4; ++ks) {
            ev[2*ks]   = *(const f32x4*)(re + ks * 32 + kq);
            ev[2*ks+1] = *(const f32x4*)(re + ks * 32 + kq + 4);
        }
        // stash e-tile to LDS (wave collectively covers all 16x128)
        #pragma unroll
        for (int ks = 0; ks < 4; ++ks) {
            *(f32x4*)(eb + m * EST + ks * 32 + kq)     = ev[2*ks];
            *(f32x4*)(eb + m * EST + ks * 32 + kq + 4) = ev[2*ks+1];
        }
        #pragma unroll
        for (int ks = 0; ks < 4; ++ks) {
            bf16x8 a;
            a[0]=f2bf(ev[2*ks][0]); a[1]=f2bf(ev[2*ks][1]); a[2]=f2bf(ev[2*ks][2]); a[3]=f2bf(ev[2*ks][3]);
            a[4]=f2bf(ev[2*ks+1][0]); a[5]=f2bf(ev[2*ks+1][1]); a[6]=f2bf(ev[2*ks+1][2]); a[7]=f2bf(ev[2*ks+1][3]);
            ae[ks] = a;
        }

        // ---------------- GEMM1: [16,384] @ [384,64] -> h[16,64] ----------------
        f32x4 acc1[4];
        #pragma unroll
        for (int nt = 0; nt < 4; ++nt) acc1[nt] = (f32x4){0.f, 0.f, 0.f, 0.f};

        #pragma unroll
        for (int ks = 0; ks < 12; ++ks) {
            bf16x8 a = (ks < 4) ? as[ks] : (ks < 8) ? ad[ks - 4] : ae[ks - 8];
            const int kglob = ks * 32 + kq;
            #pragma unroll
            for (int nt = 0; nt < 4; ++nt) {
                bf16x8 b = *(const bf16x8*)(W1T + (m + 16 * nt) * DIN + kglob);
                acc1[nt] = __builtin_amdgcn_mfma_f32_16x16x32_bf16(a, b, acc1[nt], 0, 0, 0);
            }
        }

        // bias + ReLU, h -> LDS row-major [row][hid]
        #pragma unroll
        for (int nt = 0; nt < 4; ++nt) {
            const int col = m + 16 * nt;
            const float bv = b1[col];
            #pragma unroll
            for (int r = 0; r < 4; ++r) {
                float h = acc1[nt][r] + bv;
                h = h > 0.f ? h : 0.f;
                hb[(q * 4 + r) * 72 + col] = f2bf(h);
            }
        }

        // ---------------- GEMM2: h[16,64] @ [64,128] -> [16,128] ----------------
        bf16x8 a0 = *(const bf16x8*)(hb + m * 72 + kq);
        bf16x8 a1 = *(const bf16x8*)(hb + m * 72 + 32 + kq);

        f32x4 acc2[8];
        #pragma unroll
        for (int nt = 0; nt < 8; ++nt) acc2[nt] = (f32x4){0.f, 0.f, 0.f, 0.f};

        #pragma unroll
        for (int nt = 0; nt < 8; ++nt) {
            const short* wp = W2T + (m + 16 * nt) * HID + kq;
            bf16x8 b0  = *(const bf16x8*)wp;
            bf16x8 b1v = *(const bf16x8*)(wp + 32);
            acc2[nt] = __builtin_amdgcn_mfma_f32_16x16x32_bf16(a0, b0,  acc2[nt], 0, 0, 0);
            acc2[nt] = __builtin_amdgcn_mfma_f32_16x16x32_bf16(a1, b1v, acc2[nt], 0, 0, 0);
        }

        // ---------------- epilogue: out = e(LDS) + (h@W2) + b2 ----------------
        #pragma unroll
        for (int nt = 0; nt < 8; ++nt) {
            const int d = m + 16 * nt;
            const float bv = b2[d];
            #pragma unroll
            for (int r = 0; r < 4; ++r) {
                const int row = q * 4 + r;
                out[(size_t)(ebase + row) * DN + d] = eb[row * EST + d] + acc2[nt][r] + bv;
            }
        }
    }
}

extern "C" void kernel_launch(void* const* d_in, const int* in_sizes, int n_in,
                              void* d_out, int out_size, void* d_ws, size_t ws_size,
                              hipStream_t stream) {
    const float* x  = (const float*)d_in[0];
    const int*   ei = (const int*)d_in[1];
    const float* e  = (const float*)d_in[2];
    const float* W1 = (const float*)d_in[3];
    const float* b1 = (const float*)d_in[4];
    const float* W2 = (const float*)d_in[5];
    const float* b2 = (const float*)d_in[6];
    float* out = (float*)d_out;

    short* W1T = (short*)d_ws;                 // 64*384 bf16  = 49152 B
    short* W2T = W1T + HID * DIN;              // 128*64 bf16  = 16384 B
    short* xb  = W2T + HID * DN;               // 50000*128 bf16 = 12.8 MB
    const size_t need_xb = (size_t)(HID * DIN + HID * DN + NN * DN) * 2;

    prep_weights<<<96, 256, 0, stream>>>(W1, W2, W1T, W2T);

    const int nblocks = (NTILES + 7) / 8;      // 8 tiles (128 edges) per block
    if (ws_size >= need_xb) {
        prep_x<<<(NN * DN / 8 + 255) / 256, 256, 0, stream>>>(x, xb);
        edge_update<true><<<nblocks, 256, 0, stream>>>(x, xb, ei, e, b1, b2, W1T, W2T, out);
    } else {
        edge_update<false><<<nblocks, 256, 0, stream>>>(x, xb, ei, e, b1, b2, W1T, W2T, out);
    }
}